// Round 1
// 2038.067 us; speedup vs baseline: 1.4737x; 1.4737x over previous
//
#include <hip/hip_runtime.h>
#include <hip/hip_bf16.h>

#define T_TOK   4096
#define DMODEL  2048
#define FFN     5632
#define NE      8

// ---- row/tile bookkeeping (shared by both paths) ----
#define NTILES_MAX 136          // old path: 64-row tiles
#define NT128      72           // new path: 128-row tiles (8192 + 8*127 pad -> <=9216 rows)
#define NROWS_MAX  9216

// meta layout (indices into (int*)d_ws)
#define M_CNT     0      // 8 ints
#define M_OFFS    8      // 9 ints
#define M_CUR     17     // 8 ints
#define M_TILE_E  32     // up to 136 ints
#define M_ROW_TOK 256    // 9216 ints
#define M_ROW_W   9472   // 9216 floats
#define M_TK_E    18688  // 4096 ints (e0 | e1<<16)
#define M_TK_W0   22784  // 4096 floats
#define M_TK_W1   26880  // 4096 floats

// old-path workspace layout
#define HBUF_OFF  ((size_t)1 << 20)

// new-path workspace layout (bytes)
#define XB_OFF   ((size_t)1 << 20)                  // x bf16: 16 MiB
#define HB2_OFF  ((size_t)18 << 20)                 // hbuf bf16: 9216*5632*2 = 99 MiB
#define WGB_OFF  ((size_t)122 << 20)                // Wg bf16: 176 MiB (reused for Wo later)
#define WUB_OFF  ((size_t)300 << 20)                // Wu bf16: 176 MiB
#define WS_NEED  (WUB_OFF + (size_t)NE * FFN * DMODEL * 2)   // ~476 MiB

typedef __bf16 bf16x8 __attribute__((ext_vector_type(8)));
typedef float  f32x4  __attribute__((ext_vector_type(4)));

__device__ inline void pack4_bf16(__hip_bfloat16* dst, float a, float b, float c, float d){
  union { __hip_bfloat16 h[4]; unsigned long long u; } q;
  q.h[0] = __float2bfloat16(a);
  q.h[1] = __float2bfloat16(b);
  q.h[2] = __float2bfloat16(c);
  q.h[3] = __float2bfloat16(d);
  *(unsigned long long*)dst = q.u;
}

// async global->LDS, 16B per lane; LDS dest = wave-uniform base + lane*16
__device__ inline void gl_lds16(const void* g, void* l){
  __builtin_amdgcn_global_load_lds(
      (const __attribute__((address_space(1))) unsigned int*)g,
      (__attribute__((address_space(3))) unsigned int*)l, 16, 0, 0);
}

// ---------------- init: out = bias broadcast; zero counters ----------------
__global__ __launch_bounds__(256) void k_init(float* __restrict__ out,
                                              const float* __restrict__ bias,
                                              int* __restrict__ meta){
  int idx = blockIdx.x * 256 + threadIdx.x;
  if (idx < 32) meta[idx] = 0;                 // cnt, offs, cur
  const float4* b4 = (const float4*)bias;
  int total4 = T_TOK * DMODEL / 4;
  if (idx < total4)
    ((float4*)out)[idx] = b4[idx & (DMODEL/4 - 1)];
}

// ---------------- fp32 -> bf16 bulk convert (8 elems/thread/iter) ----------------
__global__ __launch_bounds__(256) void k_cvt(const float* __restrict__ s,
                                             __hip_bfloat16* __restrict__ d,
                                             int n8){
  int i = blockIdx.x * 256 + threadIdx.x;
  int stride = gridDim.x * 256;
  for (; i < n8; i += stride){
    float4 a = ((const float4*)s)[2*i];
    float4 b = ((const float4*)s)[2*i+1];
    union { __hip_bfloat16 h[8]; uint4 u; } q;
    q.h[0]=__float2bfloat16(a.x); q.h[1]=__float2bfloat16(a.y);
    q.h[2]=__float2bfloat16(a.z); q.h[3]=__float2bfloat16(a.w);
    q.h[4]=__float2bfloat16(b.x); q.h[5]=__float2bfloat16(b.y);
    q.h[6]=__float2bfloat16(b.z); q.h[7]=__float2bfloat16(b.w);
    ((uint4*)d)[i] = q.u;
  }
}

// ---------------- router: fp32 logits, top-2, softmax, counts ----------------
__global__ __launch_bounds__(256) void k_router(const float* __restrict__ x,
                                                const float* __restrict__ gw,
                                                int* __restrict__ meta){
  int wid = threadIdx.x >> 6, lane = threadIdx.x & 63;
  int t = blockIdx.x * 4 + wid;
  float acc[NE];
  #pragma unroll
  for (int e = 0; e < NE; e++) acc[e] = 0.f;
  const float* xr = x + (size_t)t * DMODEL;
  for (int k = lane; k < DMODEL; k += 64){
    float xv = xr[k];
    #pragma unroll
    for (int e = 0; e < NE; e++) acc[e] += xv * gw[e * DMODEL + k];
  }
  #pragma unroll
  for (int e = 0; e < NE; e++){
    #pragma unroll
    for (int off = 32; off > 0; off >>= 1)
      acc[e] += __shfl_xor(acc[e], off, 64);
  }
  if (lane == 0){
    int e0 = 0; float v0 = acc[0];
    #pragma unroll
    for (int e = 1; e < NE; e++) if (acc[e] > v0){ v0 = acc[e]; e0 = e; }
    int e1 = -1; float v1 = -3.4e38f;
    #pragma unroll
    for (int e = 0; e < NE; e++) if (e != e0 && acc[e] > v1){ v1 = acc[e]; e1 = e; }
    float w0 = 1.f / (1.f + __expf(v1 - v0));   // softmax over [v0, v1]
    meta[M_TK_E + t] = e0 | (e1 << 16);
    ((float*)meta)[M_TK_W0 + t] = w0;
    ((float*)meta)[M_TK_W1 + t] = 1.f - w0;
    atomicAdd(&meta[M_CNT + e0], 1);
    atomicAdd(&meta[M_CNT + e1], 1);
  }
}

// ------------- offsets (old path): pad counts to 64, tile->expert map -------------
__global__ __launch_bounds__(256) void k_offsets64(int* __restrict__ meta){
  __shared__ int soffs[NE + 1];
  int tid = threadIdx.x;
  if (tid == 0){
    int off = 0;
    for (int e = 0; e < NE; e++){
      soffs[e] = off;
      meta[M_OFFS + e] = off;
      off += (meta[M_CNT + e] + 63) & ~63;
    }
    soffs[NE] = off;
    meta[M_OFFS + NE] = off;
  }
  __syncthreads();
  for (int i = tid; i < NTILES_MAX; i += 256){
    int r = i * 64, te = -1;
    for (int j = 0; j < NE; j++)
      if (r >= soffs[j] && r < soffs[j + 1]) te = j;
    meta[M_TILE_E + i] = te;
  }
  for (int r = tid; r < NROWS_MAX; r += 256){
    meta[M_ROW_TOK + r] = -1;
    ((float*)meta)[M_ROW_W + r] = 0.f;
  }
}

// ------------- offsets (new path): pad counts to 128, 128-row tile map -------------
// pad rows get tok=0 / weight=0 so they can be gathered safely with no branch
__global__ __launch_bounds__(256) void k_offsets128(int* __restrict__ meta){
  __shared__ int soffs[NE + 1];
  int tid = threadIdx.x;
  if (tid == 0){
    int off = 0;
    for (int e = 0; e < NE; e++){
      soffs[e] = off;
      meta[M_OFFS + e] = off;
      off += (meta[M_CNT + e] + 127) & ~127;
    }
    soffs[NE] = off;
    meta[M_OFFS + NE] = off;
  }
  __syncthreads();
  for (int i = tid; i < NT128; i += 256){
    int r = i * 128, te = -1;
    for (int j = 0; j < NE; j++)
      if (r >= soffs[j] && r < soffs[j + 1]) te = j;
    meta[M_TILE_E + i] = te;
  }
  for (int r = tid; r < NROWS_MAX; r += 256){
    meta[M_ROW_TOK + r] = 0;
    ((float*)meta)[M_ROW_W + r] = 0.f;
  }
}

// ------------- scatter tokens into compacted per-expert row lists -------------
__global__ __launch_bounds__(256) void k_scatter(int* __restrict__ meta){
  int t = blockIdx.x * 256 + threadIdx.x;
  if (t >= T_TOK) return;
  int pk = meta[M_TK_E + t];
  int e0 = pk & 0xffff, e1 = pk >> 16;
  float w0 = ((float*)meta)[M_TK_W0 + t];
  float w1 = ((float*)meta)[M_TK_W1 + t];
  int p0 = atomicAdd(&meta[M_CUR + e0], 1);
  int r0 = meta[M_OFFS + e0] + p0;
  meta[M_ROW_TOK + r0] = t;
  ((float*)meta)[M_ROW_W + r0] = w0;
  int p1 = atomicAdd(&meta[M_CUR + e1], 1);
  int r1 = meta[M_OFFS + e1] + p1;
  meta[M_ROW_TOK + r1] = t;
  ((float*)meta)[M_ROW_W + r1] = w1;
}

// =====================================================================
// NEW PATH: m97-structure GEMMs on pre-converted bf16 operands.
// 128-row tiles, BK=32, 4 waves (2x2), global_load_lds width-16 staging,
// per-lane global address does the token gather (pads -> token 0, w=0).
// =====================================================================

// pass 2: h = silu(x Wg^T) * (x Wu^T), tile 128 rows x 64 FFN cols
__global__ __launch_bounds__(256, 3) void k_ffn_in2(
    const __hip_bfloat16* __restrict__ xb,
    const __hip_bfloat16* __restrict__ wgb,
    const __hip_bfloat16* __restrict__ wub,
    const int* __restrict__ meta,
    __hip_bfloat16* __restrict__ hbuf)
{
  const int e = meta[M_TILE_E + blockIdx.y];
  if (e < 0) return;
  const int r0 = blockIdx.y * 128;
  const int n0 = blockIdx.x * 64;
  const int tid = threadIdx.x;
  const int wid = tid >> 6, lane = tid & 63, l15 = lane & 15, quad = lane >> 4;
  const int wm = wid >> 1, wn = wid & 1;          // 2x2 wave grid, wave tile 64Mx32N

  __shared__ __align__(16) __hip_bfloat16 As[128][32];
  __shared__ __align__(16) __hip_bfloat16 Bg[64][32];
  __shared__ __align__(16) __hip_bfloat16 Bu[64][32];

  const int rA = tid >> 2;                         // 0..63
  const int cb = (tid & 3) * 16;                   // byte chunk within 64B row
  const int tok0 = meta[M_ROW_TOK + r0 + rA];
  const int tok1 = meta[M_ROW_TOK + r0 + 64 + rA];
  const char* pa0 = (const char*)xb + (size_t)tok0 * (DMODEL * 2) + cb;
  const char* pa1 = (const char*)xb + (size_t)tok1 * (DMODEL * 2) + cb;
  const char* pg  = (const char*)(wgb + ((size_t)e * FFN + n0 + rA) * DMODEL) + cb;
  const char* pu  = (const char*)(wub + ((size_t)e * FFN + n0 + rA) * DMODEL) + cb;

  void* lA0 = (void*)&As[wid * 16][0];             // wave-uniform LDS bases
  void* lA1 = (void*)&As[64 + wid * 16][0];
  void* lBg = (void*)&Bg[wid * 16][0];
  void* lBu = (void*)&Bu[wid * 16][0];

  f32x4 acg[4][2], acu[4][2];
  #pragma unroll
  for (int mi = 0; mi < 4; mi++){
    #pragma unroll
    for (int ni = 0; ni < 2; ni++){
      acg[mi][ni] = (f32x4){0.f, 0.f, 0.f, 0.f};
      acu[mi][ni] = (f32x4){0.f, 0.f, 0.f, 0.f};
    }
  }

  for (int k0 = 0; k0 < DMODEL; k0 += 32){
    gl_lds16(pa0, lA0);
    gl_lds16(pa1, lA1);
    gl_lds16(pg,  lBg);
    gl_lds16(pu,  lBu);
    pa0 += 64; pa1 += 64; pg += 64; pu += 64;
    __syncthreads();                               // drains vmcnt before barrier
    bf16x8 af[4];
    #pragma unroll
    for (int mi = 0; mi < 4; mi++)
      af[mi] = *(const bf16x8*)&As[wm * 64 + mi * 16 + l15][quad * 8];
    #pragma unroll
    for (int ni = 0; ni < 2; ni++){
      bf16x8 bg = *(const bf16x8*)&Bg[wn * 32 + ni * 16 + l15][quad * 8];
      #pragma unroll
      for (int mi = 0; mi < 4; mi++)
        acg[mi][ni] = __builtin_amdgcn_mfma_f32_16x16x32_bf16(af[mi], bg, acg[mi][ni], 0, 0, 0);
      bf16x8 bu = *(const bf16x8*)&Bu[wn * 32 + ni * 16 + l15][quad * 8];
      #pragma unroll
      for (int mi = 0; mi < 4; mi++)
        acu[mi][ni] = __builtin_amdgcn_mfma_f32_16x16x32_bf16(af[mi], bu, acu[mi][ni], 0, 0, 0);
    }
    __syncthreads();
  }

  #pragma unroll
  for (int mi = 0; mi < 4; mi++){
    #pragma unroll
    for (int ni = 0; ni < 2; ni++){
      #pragma unroll
      for (int reg = 0; reg < 4; reg++){
        float g = acg[mi][ni][reg], u = acu[mi][ni][reg];
        float h = g / (1.f + __expf(-g)) * u;      // silu(g) * u
        int r = r0 + wm * 64 + mi * 16 + quad * 4 + reg;
        hbuf[(size_t)r * FFN + n0 + wn * 32 + ni * 16 + l15] = __float2bfloat16(h);
      }
    }
  }
}

// pass 3: y = h Wo^T, tile 128 rows x 128 D cols; scatter-add weight*y
__global__ __launch_bounds__(256, 3) void k_ffn_out2(
    const __hip_bfloat16* __restrict__ hbuf,
    const __hip_bfloat16* __restrict__ wob,
    const int* __restrict__ meta,
    float* __restrict__ out)
{
  const int e = meta[M_TILE_E + blockIdx.y];
  if (e < 0) return;
  const int r0 = blockIdx.y * 128;
  const int n0 = blockIdx.x * 128;
  const int tid = threadIdx.x;
  const int wid = tid >> 6, lane = tid & 63, l15 = lane & 15, quad = lane >> 4;
  const int wm = wid >> 1, wn = wid & 1;          // wave tile 64Mx64N

  __shared__ __align__(16) __hip_bfloat16 As[128][32];
  __shared__ __align__(16) __hip_bfloat16 Bs[128][32];

  const int rA = tid >> 2;
  const int cb = (tid & 3) * 16;
  const char* pa0 = (const char*)(hbuf + (size_t)(r0 + rA) * FFN) + cb;
  const char* pa1 = (const char*)(hbuf + (size_t)(r0 + 64 + rA) * FFN) + cb;
  const char* pb0 = (const char*)(wob + ((size_t)e * DMODEL + n0 + rA) * FFN) + cb;
  const char* pb1 = (const char*)(wob + ((size_t)e * DMODEL + n0 + 64 + rA) * FFN) + cb;

  void* lA0 = (void*)&As[wid * 16][0];
  void* lA1 = (void*)&As[64 + wid * 16][0];
  void* lB0 = (void*)&Bs[wid * 16][0];
  void* lB1 = (void*)&Bs[64 + wid * 16][0];

  f32x4 acc[4][4];
  #pragma unroll
  for (int mi = 0; mi < 4; mi++)
    #pragma unroll
    for (int ni = 0; ni < 4; ni++)
      acc[mi][ni] = (f32x4){0.f, 0.f, 0.f, 0.f};

  for (int k0 = 0; k0 < FFN; k0 += 32){
    gl_lds16(pa0, lA0);
    gl_lds16(pa1, lA1);
    gl_lds16(pb0, lB0);
    gl_lds16(pb1, lB1);
    pa0 += 64; pa1 += 64; pb0 += 64; pb1 += 64;
    __syncthreads();
    bf16x8 af[4];
    #pragma unroll
    for (int mi = 0; mi < 4; mi++)
      af[mi] = *(const bf16x8*)&As[wm * 64 + mi * 16 + l15][quad * 8];
    #pragma unroll
    for (int ni = 0; ni < 4; ni++){
      bf16x8 bf = *(const bf16x8*)&Bs[wn * 64 + ni * 16 + l15][quad * 8];
      #pragma unroll
      for (int mi = 0; mi < 4; mi++)
        acc[mi][ni] = __builtin_amdgcn_mfma_f32_16x16x32_bf16(af[mi], bf, acc[mi][ni], 0, 0, 0);
    }
    __syncthreads();
  }

  const float* row_w = (const float*)meta + M_ROW_W;
  #pragma unroll
  for (int mi = 0; mi < 4; mi++){
    #pragma unroll
    for (int reg = 0; reg < 4; reg++){
      int r = r0 + wm * 64 + mi * 16 + quad * 4 + reg;
      int tok = meta[M_ROW_TOK + r];
      float wgt = row_w[r];                        // pads: tok=0, wgt=0 -> adds 0
      float* orow = out + (size_t)tok * DMODEL + n0 + wn * 64;
      #pragma unroll
      for (int ni = 0; ni < 4; ni++)
        atomicAdd(&orow[ni * 16 + l15], wgt * acc[mi][ni][reg]);
    }
  }
}

// =====================================================================
// OLD PATH (fallback if workspace < ~476 MiB): previous verified kernels
// =====================================================================

__global__ __launch_bounds__(256) void k_ffn_in1(const float* __restrict__ x,
                                                 const float* __restrict__ wg_all,
                                                 const float* __restrict__ wu_all,
                                                 const int* __restrict__ meta,
                                                 __hip_bfloat16* __restrict__ hbuf){
  int e = meta[M_TILE_E + blockIdx.y];
  if (e < 0) return;
  const int r0 = blockIdx.y * 64;
  const int n0 = blockIdx.x * 64;
  const int tid = threadIdx.x;
  const int wid = tid >> 6, lane = tid & 63, l15 = lane & 15, quad = lane >> 4;

  __shared__ int toks[64];
  __shared__ __align__(16) __hip_bfloat16 As[64][40];
  __shared__ __align__(16) __hip_bfloat16 Bg[64][40];
  __shared__ __align__(16) __hip_bfloat16 Bu[64][40];

  if (tid < 64) toks[tid] = meta[M_ROW_TOK + r0 + tid];
  __syncthreads();

  const float* wg = wg_all + (size_t)e * FFN * DMODEL + (size_t)n0 * DMODEL;
  const float* wu = wu_all + (size_t)e * FFN * DMODEL + (size_t)n0 * DMODEL;

  f32x4 zero = {0.f, 0.f, 0.f, 0.f};
  f32x4 ag[4] = {zero, zero, zero, zero};
  f32x4 au[4] = {zero, zero, zero, zero};

  for (int k0 = 0; k0 < DMODEL; k0 += 32){
    for (int i = tid; i < 512; i += 256){
      int row = i >> 3, c = (i & 7) * 4;
      int tok = toks[row];
      float4 v = make_float4(0.f, 0.f, 0.f, 0.f);
      if (tok >= 0) v = *(const float4*)&x[(size_t)tok * DMODEL + k0 + c];
      pack4_bf16(&As[row][c], v.x, v.y, v.z, v.w);
      float4 g = *(const float4*)&wg[(size_t)row * DMODEL + k0 + c];
      pack4_bf16(&Bg[row][c], g.x, g.y, g.z, g.w);
      float4 u = *(const float4*)&wu[(size_t)row * DMODEL + k0 + c];
      pack4_bf16(&Bu[row][c], u.x, u.y, u.z, u.w);
    }
    __syncthreads();
    bf16x8 af = *(const bf16x8*)&As[16 * wid + l15][quad * 8];
    #pragma unroll
    for (int nt = 0; nt < 4; nt++){
      bf16x8 bg = *(const bf16x8*)&Bg[nt * 16 + l15][quad * 8];
      ag[nt] = __builtin_amdgcn_mfma_f32_16x16x32_bf16(af, bg, ag[nt], 0, 0, 0);
    }
    #pragma unroll
    for (int nt = 0; nt < 4; nt++){
      bf16x8 bu = *(const bf16x8*)&Bu[nt * 16 + l15][quad * 8];
      au[nt] = __builtin_amdgcn_mfma_f32_16x16x32_bf16(af, bu, au[nt], 0, 0, 0);
    }
    __syncthreads();
  }

  #pragma unroll
  for (int nt = 0; nt < 4; nt++){
    #pragma unroll
    for (int reg = 0; reg < 4; reg++){
      float g = ag[nt][reg], u = au[nt][reg];
      float h = g / (1.f + __expf(-g)) * u;
      int r = r0 + 16 * wid + quad * 4 + reg;
      hbuf[(size_t)r * FFN + n0 + nt * 16 + l15] = __float2bfloat16(h);
    }
  }
}

__global__ __launch_bounds__(256) void k_ffn_out1(const __hip_bfloat16* __restrict__ hbuf,
                                                  const float* __restrict__ wo_all,
                                                  const int* __restrict__ meta,
                                                  float* __restrict__ out){
  int e = meta[M_TILE_E + blockIdx.y];
  if (e < 0) return;
  const int r0 = blockIdx.y * 64;
  const int n0 = blockIdx.x * 64;
  const int tid = threadIdx.x;
  const int wid = tid >> 6, lane = tid & 63, l15 = lane & 15, quad = lane >> 4;

  __shared__ __align__(16) __hip_bfloat16 As[64][40];
  __shared__ __align__(16) __hip_bfloat16 Bs[64][40];

  const float* wo = wo_all + (size_t)e * DMODEL * FFN + (size_t)n0 * FFN;
  const float* row_w = (const float*)meta + M_ROW_W;

  f32x4 zero = {0.f, 0.f, 0.f, 0.f};
  f32x4 acc[4] = {zero, zero, zero, zero};

  const int arow = tid >> 2;
  const int ac   = (tid & 3) * 8;

  for (int k0 = 0; k0 < FFN; k0 += 32){
    *(uint4*)&As[arow][ac] = *(const uint4*)&hbuf[(size_t)(r0 + arow) * FFN + k0 + ac];
    for (int i = tid; i < 512; i += 256){
      int row = i >> 3, c = (i & 7) * 4;
      float4 v = *(const float4*)&wo[(size_t)row * FFN + k0 + c];
      pack4_bf16(&Bs[row][c], v.x, v.y, v.z, v.w);
    }
    __syncthreads();
    bf16x8 af = *(const bf16x8*)&As[16 * wid + l15][quad * 8];
    #pragma unroll
    for (int nt = 0; nt < 4; nt++){
      bf16x8 bf = *(const bf16x8*)&Bs[nt * 16 + l15][quad * 8];
      acc[nt] = __builtin_amdgcn_mfma_f32_16x16x32_bf16(af, bf, acc[nt], 0, 0, 0);
    }
    __syncthreads();
  }

  #pragma unroll
  for (int reg = 0; reg < 4; reg++){
    int r = r0 + 16 * wid + quad * 4 + reg;
    int tok = meta[M_ROW_TOK + r];
    if (tok < 0) continue;
    float wgt = row_w[r];
    #pragma unroll
    for (int nt = 0; nt < 4; nt++){
      atomicAdd(&out[(size_t)tok * DMODEL + n0 + nt * 16 + l15], wgt * acc[nt][reg]);
    }
  }
}

extern "C" void kernel_launch(void* const* d_in, const int* in_sizes, int n_in,
                              void* d_out, int out_size, void* d_ws, size_t ws_size,
                              hipStream_t stream){
  const float* x    = (const float*)d_in[0];
  const float* gw   = (const float*)d_in[1];
  const float* wg   = (const float*)d_in[2];
  const float* wu   = (const float*)d_in[3];
  const float* wo   = (const float*)d_in[4];
  const float* bias = (const float*)d_in[5];
  float* out = (float*)d_out;
  int* meta = (int*)d_ws;

  k_init<<<T_TOK * DMODEL / 4 / 256, 256, 0, stream>>>(out, bias, meta);
  k_router<<<T_TOK / 4, 256, 0, stream>>>(x, gw, meta);

  if (ws_size >= WS_NEED){
    __hip_bfloat16* xb  = (__hip_bfloat16*)((char*)d_ws + XB_OFF);
    __hip_bfloat16* hb  = (__hip_bfloat16*)((char*)d_ws + HB2_OFF);
    __hip_bfloat16* wgb = (__hip_bfloat16*)((char*)d_ws + WGB_OFF);
    __hip_bfloat16* wub = (__hip_bfloat16*)((char*)d_ws + WUB_OFF);
    __hip_bfloat16* wob = wgb;   // Wg region reused for Wo after k_ffn_in2 (stream-ordered)

    k_cvt<<<2048, 256, 0, stream>>>(x,  xb,  T_TOK * DMODEL / 8);
    k_cvt<<<4096, 256, 0, stream>>>(wg, wgb, NE * FFN * DMODEL / 8);
    k_cvt<<<4096, 256, 0, stream>>>(wu, wub, NE * FFN * DMODEL / 8);
    k_offsets128<<<1, 256, 0, stream>>>(meta);
    k_scatter<<<T_TOK / 256, 256, 0, stream>>>(meta);
    k_ffn_in2<<<dim3(FFN / 64, NT128), 256, 0, stream>>>(xb, wgb, wub, meta, hb);
    k_cvt<<<4096, 256, 0, stream>>>(wo, wob, NE * DMODEL * FFN / 8);
    k_ffn_out2<<<dim3(DMODEL / 128, NT128), 256, 0, stream>>>(hb, wob, meta, out);
  } else {
    __hip_bfloat16* hbuf = (__hip_bfloat16*)((char*)d_ws + HBUF_OFF);
    k_offsets64<<<1, 256, 0, stream>>>(meta);
    k_scatter<<<T_TOK / 256, 256, 0, stream>>>(meta);
    k_ffn_in1<<<dim3(FFN / 64, NTILES_MAX), 256, 0, stream>>>(x, wg, wu, meta, hbuf);
    k_ffn_out1<<<dim3(DMODEL / 64, NTILES_MAX), 256, 0, stream>>>(hbuf, wo, meta, out);
  }
}